// Round 9
// baseline (518.467 us; speedup 1.0000x reference)
//
#include <hip/hip_runtime.h>

typedef unsigned short ushort_t;
typedef unsigned char u8;
typedef short bf16x8 __attribute__((ext_vector_type(8)));
typedef float f32x4 __attribute__((ext_vector_type(4)));
typedef int i32x4 __attribute__((ext_vector_type(4)));

#define T_DIM 4
#define B_DIM 32
#define C_DIM 512
#define N_DIM 256

__device__ __forceinline__ float bf2f(ushort_t u) {
  union { unsigned int i; float f; } x;
  x.i = ((unsigned int)u) << 16;
  return x.f;
}
__device__ __forceinline__ ushort_t f2bf(float f) {
  unsigned int u = __float_as_uint(f);
  u = (u + 0x7FFFu + ((u >> 16) & 1u)) >> 16;
  return (ushort_t)u;
}

// async global->LDS DMA, 16B per lane, lane i lands at ldsbase + i*16
__device__ __forceinline__ void gload16(const void* g, void* l) {
  __builtin_amdgcn_global_load_lds(
      (const __attribute__((address_space(1))) unsigned int*)g,
      (__attribute__((address_space(3))) unsigned int*)l, 16, 0, 0);
}

// 0/1 spike bytes (2 per word, at bytes 0 and 2) -> 2 bf16 halfwords. (K4 only)
__device__ __forceinline__ unsigned int spike2bf(unsigned int w) {
  unsigned int r;
  asm("v_mul_u32_u24 %0, 0x3f80, %1" : "=v"(r) : "v"(w));
  return r;
}
__device__ __forceinline__ bf16x8 expand_spikes(uint2 raw) {
  union { bf16x8 v; unsigned int u[4]; } bu;
  bu.u[0] = spike2bf(__builtin_amdgcn_perm(0u, raw.x, 0x05010400u));
  bu.u[1] = spike2bf(__builtin_amdgcn_perm(0u, raw.x, 0x07030602u));
  bu.u[2] = spike2bf(__builtin_amdgcn_perm(0u, raw.y, 0x05010400u));
  bu.u[3] = spike2bf(__builtin_amdgcn_perm(0u, raw.y, 0x07030602u));
  return bu.v;
}

// ---------------------------------------------------------------------------
// K0: quantize fp32 weight rows to TWO int8 planes + per-row scale.
//   W[c][:] ~= s1_c*q1 + s2_c*q2, s1 = rowmax/127, s2 = s1/254.
//   Max error s2/2 = s1/508 (~3e-6) -- same order as bf16 2-plane split;
//   MFMA accumulation becomes exact i32.
// One wave per row; 2048 rows (Wq,Wk,Wv,Wp x 512).
// ---------------------------------------------------------------------------
__global__ __launch_bounds__(256) void k0_quant_i8(
    const float* __restrict__ Wq, const float* __restrict__ Wk,
    const float* __restrict__ Wv, const float* __restrict__ Wp,
    u8* __restrict__ SqkvI8, u8* __restrict__ SpI8,
    float* __restrict__ sQKV, float* __restrict__ sP)
{
  const int w = threadIdx.x >> 6;
  const int l = threadIdx.x & 63;
  const int row = blockIdx.x * 4 + w;   // 0..2047
  const int m = row >> 9;               // 0..3
  const int c = row & 511;
  const float* src = (m == 0) ? Wq : ((m == 1) ? Wk : ((m == 2) ? Wv : Wp));
  float wv[8];
  *(float4*)&wv[0] = *(const float4*)(src + (size_t)c * 512 + l * 8);
  *(float4*)&wv[4] = *(const float4*)(src + (size_t)c * 512 + l * 8 + 4);
  float mx = 0.f;
#pragma unroll
  for (int i = 0; i < 8; i++) mx = fmaxf(mx, fabsf(wv[i]));
#pragma unroll
  for (int off = 1; off < 64; off <<= 1) mx = fmaxf(mx, __shfl_xor(mx, off));
  const float s1   = mx * (1.0f / 127.0f);
  const float inv1 = (mx > 0.f) ? 127.0f / mx : 0.f;
  const float inv2 = inv1 * 254.0f;     // = 254/s1
  union { char cc[8]; uint2 u; } Q1, Q2;
#pragma unroll
  for (int i = 0; i < 8; i++) {
    int a = __float2int_rn(wv[i] * inv1);
    a = (a > 127) ? 127 : ((a < -127) ? -127 : a);
    float r = wv[i] - s1 * (float)a;
    int b2 = __float2int_rn(r * inv2);
    b2 = (b2 > 127) ? 127 : ((b2 < -127) ? -127 : b2);
    Q1.cc[i] = (char)a; Q2.cc[i] = (char)b2;
  }
  u8* dst = (m < 3) ? (SqkvI8 + (size_t)m * 2 * 262144) : SpI8;
  *(uint2*)(dst + (size_t)c * 512 + l * 8)          = Q1.u;
  *(uint2*)(dst + 262144 + (size_t)c * 512 + l * 8) = Q2.u;
  if (l == 0) {
    if (m < 3) sQKV[m * 512 + c] = s1; else sP[c] = s1;
  }
}

// ---------------------------------------------------------------------------
// K1: shortcut LIF on x [T,B,C,N] (fp32) -> spikes transposed xsT8 [T,B,N,C] u8
// ---------------------------------------------------------------------------
__global__ __launch_bounds__(256) void k1_shortcut_lif(
    const float* __restrict__ x, u8* __restrict__ xsT8)
{
  const int n0 = blockIdx.x * 64;
  const int c0 = blockIdx.y * 64;
  const int b  = blockIdx.z;
  __shared__ u8 sm[64][80];
  const int tid = threadIdx.x;
  const int r  = tid >> 2;
  const int j0 = (tid & 3) * 16;
  float v[16];
#pragma unroll
  for (int i = 0; i < 16; i++) v[i] = 0.f;
  for (int t = 0; t < T_DIM; t++) {
    const float* xp = x + ((((size_t)t * B_DIM + b) * C_DIM) + c0 + r) * N_DIM + n0 + j0;
    float xv[16];
    *(float4*)&xv[0]  = *(const float4*)xp;
    *(float4*)&xv[4]  = *(const float4*)(xp + 4);
    *(float4*)&xv[8]  = *(const float4*)(xp + 8);
    *(float4*)&xv[12] = *(const float4*)(xp + 12);
    __syncthreads();
#pragma unroll
    for (int i = 0; i < 16; i++) {
      float nv = v[i] + (xv[i] - v[i]) * 0.5f;
      bool s = (nv >= 1.0f);
      v[i] = s ? 0.f : nv;
      sm[j0 + i][r] = s ? (u8)1 : (u8)0;
    }
    __syncthreads();
    union { uint4 u; u8 b[16]; } ov;
#pragma unroll
    for (int i = 0; i < 16; i++) ov.b[i] = sm[r][j0 + i];
    u8* op = xsT8 + ((((size_t)t * B_DIM + b) * N_DIM) + n0 + r) * C_DIM + c0 + j0;
    *(uint4*)op = ov.u;
  }
}

// ---------------------------------------------------------------------------
// K2: QKV conv1x1 + BN + LIF -- INT8 MFMA engine. 512 threads (8 waves),
// 64m x 256n block tile, wave tile 32m x 64n. TWO i8 weight planes, spikes
// consumed as raw i8 (NO expansion VALU). mfma_i32_16x16x32_i8, dual i32
// acc sets (exact), scales folded at epilogue: y = a1*(s1*sc)+a2*(s2*sc)+bi.
// 32-byte LDS rows (A and B identical geometry); pair-preserving swizzle
// half16' = half16 ^ row-bit3 (2-way residual = free). Depth-2 counted-vmcnt
// pipeline, 4 rotating buffers (48 KB), 1 s_barrier/step. Staging: waves 0-3
// stage 1 A + 1 B chunk (L=2), waves 4-7 stage 1 B chunk (L=1).
// Outputs: q->qs8T[t,b,n,c]; k->ks8[t,b,c,n]; v->vout fp32 + vs8T[t,b,h,e,n].
// ---------------------------------------------------------------------------
__global__ __launch_bounds__(512, 4) void k2_qkv(
    const u8* __restrict__ xsT8, const u8* __restrict__ SqkvI8,
    const float* __restrict__ sQKV,
    const float* __restrict__ qsc, const float* __restrict__ qbi,
    const float* __restrict__ ksc, const float* __restrict__ kbi,
    const float* __restrict__ vsc, const float* __restrict__ vbi,
    u8* __restrict__ qs8T, u8* __restrict__ ks8, float* __restrict__ vout,
    u8* __restrict__ vs8T)
{
  const int lin = blockIdx.x + blockIdx.y * 24;        // 0..767
  const int b   = (lin & 7) | (((lin >> 3) & 3) << 3); // XCD = lin%8 = b%8
  const int mt  = lin >> 5;                            // 0..23
  const int branch = mt >> 3;
  const int mloc = (mt & 7) * 64;
  const u8* Wi8 = SqkvI8 + (size_t)branch * 2 * 262144;
  const float* s1p = sQKV + branch * 512;
  const float* scp = (branch == 0) ? qsc : ((branch == 1) ? ksc : vsc);
  const float* bip = (branch == 0) ? qbi : ((branch == 1) ? kbi : vbi);

  __shared__ alignas(16) u8 As8[4][2][64][32];   // 16 KB
  __shared__ alignas(16) u8 Bs8[4][256][32];     // 32 KB

  const int tid  = threadIdx.x;
  const int lane = tid & 63;
  const int wave = tid >> 6;
  const int wm   = wave >> 2;          // 0..1 m-strip (32 rows)
  const int wn   = wave & 3;           // 0..3 n-strip (64 cols)
  const int frow = lane & 15;
  const int fsl  = lane >> 4;          // 8B slot 0..3
  // frag swizzle: slot8' = slot8 ^ (row_bit3 << 1); row bit3 == frow bit3.
  const int off8 = (fsl ^ (((frow >> 3) & 1) << 1)) * 8;
  // stage-side pre-swizzle: lane covers row l>>1, half16 l&1; row bit3 = (l>>4)&1.
  const int hsw  = (((lane & 1) ^ ((lane >> 4) & 1)) * 16);
  const int srow = lane >> 1;          // row within 32-row chunk

  const u8* Bb0 = xsT8 + (size_t)b * N_DIM * C_DIM;

#define K2_STAGE(s_) {                                                                     \
    const int ss_ = (s_);                                                                  \
    const int t_ = ss_ >> 4; const int kb_ = (ss_ & 15) * 32; const int bf_ = ss_ & 3;     \
    if (wave < 4)                                                                          \
      gload16(Wi8 + (size_t)(wave >> 1) * 262144 +                                         \
              (size_t)(mloc + (wave & 1) * 32 + srow) * 512 + kb_ + hsw,                   \
              &As8[bf_][wave >> 1][(wave & 1) * 32][0]);                                   \
    gload16(Bb0 + (size_t)t_ * (B_DIM * N_DIM * C_DIM) +                                   \
            (size_t)(wave * 32 + srow) * 512 + kb_ + hsw,                                  \
            &Bs8[bf_][wave * 32][0]);                                                      \
  }

  i32x4 accA[8], accB[8];
  float vst[32];
#pragma unroll
  for (int i = 0; i < 32; i++) vst[i] = 0.f;
#pragma unroll
  for (int j = 0; j < 8; j++) { accA[j] = (i32x4){0,0,0,0}; accB[j] = (i32x4){0,0,0,0}; }

  const int crow0 = (lane >> 4) * 4;
  const int cn    = lane & 15;
  float G1[2][4], G2[2][4], bi8[2][4];
#pragma unroll
  for (int mi = 0; mi < 2; mi++)
#pragma unroll
    for (int r = 0; r < 4; r++) {
      int c = mloc + wm * 32 + mi * 16 + crow0 + r;
      float s1 = s1p[c], sc = scp[c];
      G1[mi][r] = s1 * sc;
      G2[mi][r] = s1 * (1.0f / 254.0f) * sc;
      bi8[mi][r] = bip[c];
    }

  K2_STAGE(0);
  K2_STAGE(1);

  for (int s = 0; s < 64; s++) {
    const int cur = s & 3;
    if (s < 62) K2_STAGE(s + 2);

    if (s < 62) {
      if (wave < 4) asm volatile("s_waitcnt vmcnt(4)" ::: "memory");
      else          asm volatile("s_waitcnt vmcnt(2)" ::: "memory");
    } else if (s == 62) {
      if (wave < 4) asm volatile("s_waitcnt vmcnt(2)" ::: "memory");
      else          asm volatile("s_waitcnt vmcnt(1)" ::: "memory");
    } else {
      asm volatile("s_waitcnt vmcnt(0)" ::: "memory");
    }
    __builtin_amdgcn_s_barrier();
    __builtin_amdgcn_sched_barrier(0);

    long bl[4];
#pragma unroll
    for (int nj = 0; nj < 4; nj++)
      bl[nj] = *(const long*)&Bs8[cur][wn * 64 + nj * 16 + frow][off8];

#pragma unroll
    for (int mi = 0; mi < 2; mi++) {
      const int ar = wm * 32 + mi * 16 + frow;
      const long p0 = *(const long*)&As8[cur][0][ar][off8];
      const long p1 = *(const long*)&As8[cur][1][ar][off8];
#pragma unroll
      for (int nj = 0; nj < 4; nj++) {
        accA[mi * 4 + nj] = __builtin_amdgcn_mfma_i32_16x16x32_i8(p0, bl[nj], accA[mi * 4 + nj], 0, 0, 0);
        accB[mi * 4 + nj] = __builtin_amdgcn_mfma_i32_16x16x32_i8(p1, bl[nj], accB[mi * 4 + nj], 0, 0, 0);
      }
    }

    if ((s & 15) == 15) {
      const int t = s >> 4;
      const size_t tb = (size_t)t * B_DIM + b;
      if (branch == 0) {
#pragma unroll
        for (int mi = 0; mi < 2; mi++) {
          const int c0 = mloc + wm * 32 + mi * 16 + crow0;
#pragma unroll
          for (int nj = 0; nj < 4; nj++) {
            const int n = wn * 64 + nj * 16 + cn;
            u8 sv[4];
#pragma unroll
            for (int r = 0; r < 4; r++) {
              float y = (float)accA[mi * 4 + nj][r] * G1[mi][r]
                      + (float)accB[mi * 4 + nj][r] * G2[mi][r] + bi8[mi][r];
              const int vi = (mi * 4 + nj) * 4 + r;
              float v = vst[vi];
              v = v + (y - v) * 0.5f;
              bool sp = (v >= 1.0f);
              vst[vi] = sp ? 0.f : v;
              sv[r] = sp ? (u8)1 : (u8)0;
            }
            *(uchar4*)(qs8T + (tb * N_DIM + n) * C_DIM + c0) =
                make_uchar4(sv[0], sv[1], sv[2], sv[3]);
          }
        }
      } else if (branch == 1) {
#pragma unroll
        for (int mi = 0; mi < 2; mi++)
#pragma unroll
          for (int r = 0; r < 4; r++) {
            const int c = mloc + wm * 32 + mi * 16 + crow0 + r;
#pragma unroll
            for (int nj = 0; nj < 4; nj++) {
              const int n = wn * 64 + nj * 16 + cn;
              float y = (float)accA[mi * 4 + nj][r] * G1[mi][r]
                      + (float)accB[mi * 4 + nj][r] * G2[mi][r] + bi8[mi][r];
              const int vi = (mi * 4 + nj) * 4 + r;
              float v = vst[vi];
              v = v + (y - v) * 0.5f;
              bool sp = (v >= 1.0f);
              vst[vi] = sp ? 0.f : v;
              ks8[(tb * C_DIM + c) * N_DIM + n] = sp ? (u8)1 : (u8)0;
            }
          }
      } else {
        const int hv = mloc >> 6;
#pragma unroll
        for (int mi = 0; mi < 2; mi++) {
          const int d0 = wm * 32 + mi * 16 + crow0;
#pragma unroll
          for (int nj = 0; nj < 4; nj++) {
            const int n = wn * 64 + nj * 16 + cn;
            float ov[4];
            u8 sv[4];
#pragma unroll
            for (int r = 0; r < 4; r++) {
              float y = (float)accA[mi * 4 + nj][r] * G1[mi][r]
                      + (float)accB[mi * 4 + nj][r] * G2[mi][r] + bi8[mi][r];
              const int vi = (mi * 4 + nj) * 4 + r;
              float v = vst[vi];
              v = v + (y - v) * 0.5f;
              bool sp = (v >= 1.0f);
              vst[vi] = sp ? 0.f : v;
              ov[r] = sp ? 1.0f : 0.0f;
              sv[r] = sp ? (u8)1 : (u8)0;
            }
            *(float4*)(vout + ((tb * 8 + hv) * N_DIM + n) * 64 + d0) =
                make_float4(ov[0], ov[1], ov[2], ov[3]);
#pragma unroll
            for (int r = 0; r < 4; r++)
              vs8T[((tb * 8 + hv) * 64 + d0 + r) * N_DIM + n] = sv[r];
          }
        }
      }
#pragma unroll
      for (int j = 0; j < 8; j++) { accA[j] = (i32x4){0,0,0,0}; accB[j] = (i32x4){0,0,0,0}; }
    }
  }
#undef K2_STAGE
}

// ---------------------------------------------------------------------------
// K3 (i8 MFMA, exact): attn[d,e] = (1/16) * sum_{t,n} K[d,tn]*V[tn,e].
// Both operands 0/1 spikes consumed raw as i8; i32 acc = exact counts.
// 4 waves, 16 k-steps of 32, depth-2 counted-vmcnt, 32B-row swizzled LDS.
// Output attnT2 = attn^T as exact 2-plane bf16, layout [blk][p][ks2][e][32d].
// ---------------------------------------------------------------------------
__global__ __launch_bounds__(256) void k3_attn(
    const u8* __restrict__ ks8, const u8* __restrict__ vs8T,
    ushort_t* __restrict__ attnT2)
{
  const int h  = blockIdx.x;
  const int b  = blockIdx.y;
  const int ch = blockIdx.z;
  __shared__ alignas(16) u8 Ks[4][64][32];
  __shared__ alignas(16) u8 Vs[4][64][32];
  const int tid  = threadIdx.x;
  const int lane = tid & 63;
  const int wave = tid >> 6;        // 0..3
  const int frow = lane & 15;
  const int fsl  = lane >> 4;
  const int off8 = (fsl ^ (((frow >> 3) & 1) << 1)) * 8;
  const int hsw  = (((lane & 1) ^ ((lane >> 4) & 1)) * 16);
  const int srow = lane >> 1;

#define K3_STAGE(s_) {                                                                     \
    const int ss_ = (s_);                                                                  \
    const int t_ = ch * 2 + (ss_ >> 3); const int kb_ = (ss_ & 7) * 32; const int bf_ = ss_ & 3; \
    if (wave < 2)                                                                          \
      gload16(ks8 + ((((size_t)t_ * B_DIM + b) * C_DIM) + h * 64 + wave * 32 + srow) * N_DIM + kb_ + hsw, \
              &Ks[bf_][wave * 32][0]);                                                     \
    else                                                                                   \
      gload16(vs8T + ((((size_t)t_ * B_DIM + b) * 8 + h) * 64 + (wave - 2) * 32 + srow) * N_DIM + kb_ + hsw, \
              &Vs[bf_][(wave - 2) * 32][0]);                                               \
  }

  i32x4 acc[4];
#pragma unroll
  for (int i = 0; i < 4; i++) acc[i] = (i32x4){0,0,0,0};

  K3_STAGE(0);
  K3_STAGE(1);

  for (int s = 0; s < 16; s++) {
    const int cur = s & 3;
    if (s < 14) K3_STAGE(s + 2);

    if (s < 14)       asm volatile("s_waitcnt vmcnt(2)" ::: "memory");
    else if (s == 14) asm volatile("s_waitcnt vmcnt(1)" ::: "memory");
    else              asm volatile("s_waitcnt vmcnt(0)" ::: "memory");
    __builtin_amdgcn_s_barrier();
    __builtin_amdgcn_sched_barrier(0);

    const long aK = *(const long*)&Ks[cur][wave * 16 + frow][off8];
#pragma unroll
    for (int nt = 0; nt < 4; nt++) {
      const long bV = *(const long*)&Vs[cur][nt * 16 + frow][off8];
      acc[nt] = __builtin_amdgcn_mfma_i32_16x16x32_i8(aK, bV, acc[nt], 0, 0, 0);
    }
  }

  // epilogue: C[d][e] -> attnT2[e][d] as 2 exact bf16 planes.
  const int cn    = lane & 15;
  const int crow0 = (lane >> 4) * 4;
  const int d     = wave * 16 + crow0;
  const int ks2   = d >> 5;
  const int dl    = d & 31;
  const size_t blk = ((size_t)(ch * B_DIM + b) * 8 + h);
#pragma unroll
  for (int nt = 0; nt < 4; nt++) {
    const int e = nt * 16 + cn;
    union { ushort_t sv[4]; uint2 u; } H, M;
#pragma unroll
    for (int r = 0; r < 4; r++) {
      float a = (float)acc[nt][r] * 0.0625f;
      ushort_t hi = f2bf(a);
      float m = a - bf2f(hi);
      H.sv[r] = hi;
      M.sv[r] = f2bf(m);
    }
    *(uint2*)(attnT2 + ((blk * 2 + 0) * 2 + ks2) * 2048 + (size_t)e * 32 + dl) = H.u;
    *(uint2*)(attnT2 + ((blk * 2 + 1) * 2 + ks2) * 2048 + (size_t)e * 32 + dl) = M.u;
  }
#undef K3_STAGE
}

// ---------------------------------------------------------------------------
// K4 (bf16 MFMA): out[e,n] = sum_d attnT[e,d]*q[d,n]; LIF(0.5) over t;
// -> x2sT8[t,b,n,c] u8. Unchanged from round 7/8 (exact math).
// ---------------------------------------------------------------------------
__global__ __launch_bounds__(256) void k4_out_lif(
    const u8* __restrict__ qs8T, const ushort_t* __restrict__ attnT2,
    u8* __restrict__ x2sT8)
{
  const int h  = blockIdx.x;
  const int b  = blockIdx.y;
  const int nc = blockIdx.z;   // 0..1
  __shared__ alignas(16) ushort_t As[2][2][2][64][32];  // [ch][p][ks][e][32d] 32 KB
  __shared__ alignas(16) u8 Bs[2][128][32];             // 8 KB
  const int tid  = threadIdx.x;
  const int lane = tid & 63;
  const int wave = tid >> 6;        // 0..3
  const int wrow = wave * 16;       // e strip
  const int frow = lane & 15;
  const int fsl  = lane >> 4;
  const int arl  = lane >> 2;
  const int acl  = (((lane & 3) ^ ((arl >> 1) & 3)) * 8);
  const int brl  = lane >> 1;
  const int bcl  = (((lane & 1) ^ ((brl >> 2) & 1) ^ ((brl >> 3) & 1)) * 16);

#define K4_STAGEB(s_) {                                                                    \
    const int ss_ = (s_); const int t_ = ss_ >> 1; const int ks_ = ss_ & 1;                \
    gload16(qs8T + (((size_t)t_ * B_DIM + b) * N_DIM + nc * 128 + wave * 32 + brl) * C_DIM \
                 + h * 64 + ks_ * 32 + bcl,                                                \
            &Bs[ss_ & 1][wave * 32][0]);                                                   \
  }

#pragma unroll
  for (int i = 0; i < 8; i++) {
    const int c  = wave * 8 + i;
    const int chb = c >> 4, c4 = c & 15;
    const int p = c4 >> 3, ks = (c4 >> 2) & 1, g = c4 & 3;
    const size_t blk = ((size_t)(chb * B_DIM + b) * 8 + h);
    gload16(attnT2 + (((blk * 2 + p) * 2 + ks) * 64 + g * 16 + arl) * 32 + acl,
            &As[chb][p][ks][g * 16][0]);
  }
  K4_STAGEB(0);
  asm volatile("s_waitcnt vmcnt(0)" ::: "memory");
  __builtin_amdgcn_s_barrier();
  __builtin_amdgcn_sched_barrier(0);

  f32x4 acc[8];
  float vst[32];
#pragma unroll
  for (int i = 0; i < 32; i++) vst[i] = 0.f;

  const int cn    = lane & 15;
  const int crow0 = (lane >> 4) * 4;

  for (int sg = 0; sg < 8; sg++) {
    const int cur = sg & 1;
    if (sg < 7) K4_STAGEB(sg + 1);

    const int chb = sg >> 2, ks = sg & 1;
    if (ks == 0) {
#pragma unroll
      for (int j = 0; j < 8; j++) acc[j] = (f32x4){0.f, 0.f, 0.f, 0.f};
    }

    bf16x8 af[2];
    const int ar = wrow + frow;
    const int asw = (fsl ^ ((ar >> 1) & 3)) * 8;
#pragma unroll
    for (int p = 0; p < 2; p++) af[p] = *(const bf16x8*)&As[chb][p][ks][ar][asw];

#pragma unroll
    for (int j = 0; j < 8; j++) {
      const int row = j * 16 + frow;
      const int bx  = ((row >> 2) ^ (row >> 3)) & 1;
      const int bsw = (((fsl >> 1) ^ bx) << 4) + ((fsl & 1) << 3);
      bf16x8 bv = expand_spikes(*(const uint2*)&Bs[cur][row][bsw]);
#pragma unroll
      for (int p = 0; p < 2; p++)
        acc[j] = __builtin_amdgcn_mfma_f32_16x16x32_bf16(af[p], bv, acc[j], 0, 0, 0);
    }

    if (ks == 1) {
      const int t = sg >> 1;
      const size_t tb = (size_t)t * B_DIM + b;
#pragma unroll
      for (int j = 0; j < 8; j++) {
        const int n = nc * 128 + j * 16 + cn;
        u8 sv[4];
#pragma unroll
        for (int r = 0; r < 4; r++) {
          const int vi = j * 4 + r;
          float y = acc[j][r];
          float nv = vst[vi] + (y - vst[vi]) * 0.5f;
          bool sp = (nv >= 0.5f);
          vst[vi] = sp ? 0.f : nv;
          sv[r] = sp ? (u8)1 : (u8)0;
        }
        *(uchar4*)(x2sT8 + (tb * N_DIM + n) * C_DIM + h * 64 + wrow + crow0) =
            make_uchar4(sv[0], sv[1], sv[2], sv[3]);
      }
    }

    asm volatile("s_waitcnt vmcnt(0)" ::: "memory");
    __builtin_amdgcn_s_barrier();
    __builtin_amdgcn_sched_barrier(0);
  }
#undef K4_STAGEB
}

// ---------------------------------------------------------------------------
// K5: proj conv1x1 (+bp)*scale+bias + residual -> out0 fp32. Same i8 engine
// as K2 (2 i8 planes from SpI8 + sP scales). Grid (tb, mt): XCD = tb%8.
// out = a1*(s1*sc) + a2*(s2*sc) + (bp*sc + bi) + x.
// ---------------------------------------------------------------------------
__global__ __launch_bounds__(512, 4) void k5_proj(
    const u8* __restrict__ x2sT8, const u8* __restrict__ SpI8,
    const float* __restrict__ sP,
    const float* __restrict__ bp, const float* __restrict__ psc,
    const float* __restrict__ pbi,
    const float* __restrict__ x, float* __restrict__ out0)
{
  const int tb = blockIdx.x;   // 0..127 (fast dim -> XCD = tb%8)
  const int mt = blockIdx.y;   // 0..7
  const int mloc = mt * 64;

  __shared__ alignas(16) u8 As8[4][2][64][32];
  __shared__ alignas(16) u8 Bs8[4][256][32];

  const int tid  = threadIdx.x;
  const int lane = tid & 63;
  const int wave = tid >> 6;
  const int wm   = wave >> 2;
  const int wn   = wave & 3;
  const int frow = lane & 15;
  const int fsl  = lane >> 4;
  const int off8 = (fsl ^ (((frow >> 3) & 1) << 1)) * 8;
  const int hsw  = (((lane & 1) ^ ((lane >> 4) & 1)) * 16);
  const int srow = lane >> 1;

  const u8* Bb = x2sT8 + (size_t)tb * N_DIM * C_DIM;

#define K5_STAGE(s_) {                                                                     \
    const int ss_ = (s_); const int kb_ = ss_ * 32; const int bf_ = ss_ & 3;               \
    if (wave < 4)                                                                          \
      gload16(SpI8 + (size_t)(wave >> 1) * 262144 +                                        \
              (size_t)(mloc + (wave & 1) * 32 + srow) * 512 + kb_ + hsw,                   \
              &As8[bf_][wave >> 1][(wave & 1) * 32][0]);                                   \
    gload16(Bb + (size_t)(wave * 32 + srow) * 512 + kb_ + hsw, &Bs8[bf_][wave * 32][0]);   \
  }

  i32x4 accA[8], accB[8];
#pragma unroll
  for (int j = 0; j < 8; j++) { accA[j] = (i32x4){0,0,0,0}; accB[j] = (i32x4){0,0,0,0}; }

  K5_STAGE(0);
  K5_STAGE(1);

  for (int s = 0; s < 16; s++) {
    const int cur = s & 3;
    if (s < 14) K5_STAGE(s + 2);

    if (s < 14) {
      if (wave < 4) asm volatile("s_waitcnt vmcnt(4)" ::: "memory");
      else          asm volatile("s_waitcnt vmcnt(2)" ::: "memory");
    } else if (s == 14) {
      if (wave < 4) asm volatile("s_waitcnt vmcnt(2)" ::: "memory");
      else          asm volatile("s_waitcnt vmcnt(1)" ::: "memory");
    } else {
      asm volatile("s_waitcnt vmcnt(0)" ::: "memory");
    }
    __builtin_amdgcn_s_barrier();
    __builtin_amdgcn_sched_barrier(0);

    long bl[4];
#pragma unroll
    for (int nj = 0; nj < 4; nj++)
      bl[nj] = *(const long*)&Bs8[cur][wn * 64 + nj * 16 + frow][off8];

#pragma unroll
    for (int mi = 0; mi < 2; mi++) {
      const int ar = wm * 32 + mi * 16 + frow;
      const long p0 = *(const long*)&As8[cur][0][ar][off8];
      const long p1 = *(const long*)&As8[cur][1][ar][off8];
#pragma unroll
      for (int nj = 0; nj < 4; nj++) {
        accA[mi * 4 + nj] = __builtin_amdgcn_mfma_i32_16x16x32_i8(p0, bl[nj], accA[mi * 4 + nj], 0, 0, 0);
        accB[mi * 4 + nj] = __builtin_amdgcn_mfma_i32_16x16x32_i8(p1, bl[nj], accB[mi * 4 + nj], 0, 0, 0);
      }
    }
  }

  const int crow0 = (lane >> 4) * 4;
  const int cn    = lane & 15;
#pragma unroll
  for (int mi = 0; mi < 2; mi++)
#pragma unroll
    for (int r = 0; r < 4; r++) {
      const int c = mloc + wm * 32 + mi * 16 + crow0 + r;
      const float s1 = sP[c];
      const float scf = psc[c];
      const float g1 = s1 * scf;
      const float g2 = s1 * (1.0f / 254.0f) * scf;
      const float b0 = bp[c] * scf + pbi[c];
#pragma unroll
      for (int nj = 0; nj < 4; nj++) {
        const int n = wn * 64 + nj * 16 + cn;
        const size_t idx = ((size_t)tb * C_DIM + c) * N_DIM + n;
        out0[idx] = (float)accA[mi * 4 + nj][r] * g1
                  + (float)accB[mi * 4 + nj][r] * g2 + b0 + x[idx];
      }
    }
#undef K5_STAGE
}

// ---------------------------------------------------------------------------
// Memory map (race-free):
// d_out (128 MB): out0 bytes [0,64M) scratch until K5:
//   [0,16M)  xsT8 [K1->K2]   ; attnT2 8MB reuses [0,8M) [K3->K4] (xsT8 dead)
//   [16,32M) qs8T [K2->K4]
//   [32,48M) ks8  [K2->K3]
//   [48,64M) vs8T [K2->K3]
// out1 bytes [64,128M) = vout (fp32 v output, written by K2).
// d_ws: [0,16M) x2sT8 [K4->K5]; SqkvI8 1.5MB + sQKV 6KB alias [0,~1.6M)
//       [K0->K2] (safe: K2 reads before K4 writes x2sT8).
//       [16M,16M+514K) SpI8 512KB + sP 2KB [K0->K5].
// ---------------------------------------------------------------------------
extern "C" void kernel_launch(void* const* d_in, const int* in_sizes, int n_in,
                              void* d_out, int out_size, void* d_ws, size_t ws_size,
                              hipStream_t stream) {
  const float* x   = (const float*)d_in[0];
  const float* Wq  = (const float*)d_in[1];
  const float* qsc = (const float*)d_in[2];
  const float* qbi = (const float*)d_in[3];
  const float* Wk  = (const float*)d_in[4];
  const float* ksc = (const float*)d_in[5];
  const float* kbi = (const float*)d_in[6];
  const float* Wv  = (const float*)d_in[7];
  const float* vsc = (const float*)d_in[8];
  const float* vbi = (const float*)d_in[9];
  const float* Wp  = (const float*)d_in[10];
  const float* bp  = (const float*)d_in[11];
  const float* psc = (const float*)d_in[12];
  const float* pbi = (const float*)d_in[13];

  float* out0 = (float*)d_out;
  float* out1 = out0 + 16777216;

  const size_t M16 = 16u * 1024u * 1024u;
  char* o0 = (char*)d_out;
  char* ws = (char*)d_ws;

  u8*       xsT8   = (u8*)(o0);
  ushort_t* attnT2 = (ushort_t*)(o0);
  u8*       qs8T   = (u8*)(o0 + M16);
  u8*       ks8    = (u8*)(o0 + 2 * M16);
  u8*       vs8T   = (u8*)(o0 + 3 * M16);
  u8*       x2sT8  = (u8*)(ws);
  u8*       SqkvI8 = (u8*)(ws);
  float*    sQKV   = (float*)(ws + 3 * 2 * 262144);
  u8*       SpI8   = (u8*)(ws + M16);
  float*    sP     = (float*)(ws + M16 + 2 * 262144);

  hipLaunchKernelGGL(k0_quant_i8,     dim3(512),        dim3(256), 0, stream,
                     Wq, Wk, Wv, Wp, SqkvI8, SpI8, sQKV, sP);
  hipLaunchKernelGGL(k1_shortcut_lif, dim3(4, 8, 32),   dim3(256), 0, stream, x, xsT8);
  hipLaunchKernelGGL(k2_qkv,          dim3(24, 32),     dim3(512), 0, stream,
                     xsT8, SqkvI8, sQKV, qsc, qbi, ksc, kbi, vsc, vbi,
                     qs8T, ks8, out1, vs8T);
  hipLaunchKernelGGL(k3_attn,         dim3(8, 32, 2),   dim3(256), 0, stream,
                     ks8, vs8T, attnT2);
  hipLaunchKernelGGL(k4_out_lif,      dim3(8, 32, 2),   dim3(256), 0, stream,
                     qs8T, attnT2, x2sT8);
  hipLaunchKernelGGL(k5_proj,         dim3(128, 8),     dim3(512), 0, stream,
                     x2sT8, SpI8, sP, bp, psc, pbi, x, out0);
}

// Round 12
// 425.911 us; speedup vs baseline: 1.2173x; 1.2173x over previous
//
#include <hip/hip_runtime.h>

typedef unsigned short ushort_t;
typedef unsigned char u8;
typedef short bf16x8 __attribute__((ext_vector_type(8)));
typedef float f32x4 __attribute__((ext_vector_type(4)));
typedef int i32x4 __attribute__((ext_vector_type(4)));

#define T_DIM 4
#define B_DIM 32
#define C_DIM 512
#define N_DIM 256

__device__ __forceinline__ float bf2f(ushort_t u) {
  union { unsigned int i; float f; } x;
  x.i = ((unsigned int)u) << 16;
  return x.f;
}
__device__ __forceinline__ ushort_t f2bf(float f) {
  unsigned int u = __float_as_uint(f);
  u = (u + 0x7FFFu + ((u >> 16) & 1u)) >> 16;
  return (ushort_t)u;
}

// async global->LDS DMA, 16B per lane, lane i lands at ldsbase + i*16
__device__ __forceinline__ void gload16(const void* g, void* l) {
  __builtin_amdgcn_global_load_lds(
      (const __attribute__((address_space(1))) unsigned int*)g,
      (__attribute__((address_space(3))) unsigned int*)l, 16, 0, 0);
}

// 0/1 spike bytes (2 per word, at bytes 0 and 2) -> 2 bf16 halfwords.
__device__ __forceinline__ unsigned int spike2bf(unsigned int w) {
  unsigned int r;
  asm("v_mul_u32_u24 %0, 0x3f80, %1" : "=v"(r) : "v"(w));
  return r;
}
__device__ __forceinline__ bf16x8 expand_spikes(uint2 raw) {
  union { bf16x8 v; unsigned int u[4]; } bu;
  bu.u[0] = spike2bf(__builtin_amdgcn_perm(0u, raw.x, 0x05010400u));
  bu.u[1] = spike2bf(__builtin_amdgcn_perm(0u, raw.x, 0x07030602u));
  bu.u[2] = spike2bf(__builtin_amdgcn_perm(0u, raw.y, 0x05010400u));
  bu.u[3] = spike2bf(__builtin_amdgcn_perm(0u, raw.y, 0x07030602u));
  return bu.v;
}

// ---------------------------------------------------------------------------
// K0: split fp32 weights into 3 bf16 planes (hi, mid, lo). W ~= hi+mid+lo.
// (K2/K5 consume only hi+mid.)
// ---------------------------------------------------------------------------
__global__ __launch_bounds__(256) void k0_split(
    const float* __restrict__ Wq, const float* __restrict__ Wk,
    const float* __restrict__ Wv, const float* __restrict__ Wp,
    ushort_t* __restrict__ Sqkv, ushort_t* __restrict__ Sp)
{
  int gid = blockIdx.x * 256 + threadIdx.x;   // [0, 131072)
  int w = gid >> 15;
  int off = (gid & 32767) * 8;
  const float* src = (w == 0) ? Wq : ((w == 1) ? Wk : ((w == 2) ? Wv : Wp));
  ushort_t* dst = (w < 3) ? (Sqkv + (size_t)w * 3 * 262144) : Sp;
  float wv[8];
  *(float4*)&wv[0] = *(const float4*)(src + off);
  *(float4*)&wv[4] = *(const float4*)(src + off + 4);
  ushort_t hi[8], mi[8], lo[8];
#pragma unroll
  for (int i = 0; i < 8; i++) {
    float f = wv[i];
    ushort_t h = f2bf(f);  float r  = f - bf2f(h);
    ushort_t m = f2bf(r);  float r2 = r - bf2f(m);
    ushort_t l = f2bf(r2);
    hi[i] = h; mi[i] = m; lo[i] = l;
  }
  *(uint4*)(dst + off)              = *(uint4*)&hi[0];
  *(uint4*)(dst + 262144 + off)     = *(uint4*)&mi[0];
  *(uint4*)(dst + 2 * 262144 + off) = *(uint4*)&lo[0];
}

// ---------------------------------------------------------------------------
// K1: shortcut LIF on x [T,B,C,N] (fp32) -> spikes transposed xsT8 [T,B,N,C] u8
// ---------------------------------------------------------------------------
__global__ __launch_bounds__(256) void k1_shortcut_lif(
    const float* __restrict__ x, u8* __restrict__ xsT8)
{
  const int n0 = blockIdx.x * 64;
  const int c0 = blockIdx.y * 64;
  const int b  = blockIdx.z;
  __shared__ u8 sm[64][80];
  const int tid = threadIdx.x;
  const int r  = tid >> 2;
  const int j0 = (tid & 3) * 16;
  float v[16];
#pragma unroll
  for (int i = 0; i < 16; i++) v[i] = 0.f;
  for (int t = 0; t < T_DIM; t++) {
    const float* xp = x + ((((size_t)t * B_DIM + b) * C_DIM) + c0 + r) * N_DIM + n0 + j0;
    float xv[16];
    *(float4*)&xv[0]  = *(const float4*)xp;
    *(float4*)&xv[4]  = *(const float4*)(xp + 4);
    *(float4*)&xv[8]  = *(const float4*)(xp + 8);
    *(float4*)&xv[12] = *(const float4*)(xp + 12);
    __syncthreads();
#pragma unroll
    for (int i = 0; i < 16; i++) {
      float nv = v[i] + (xv[i] - v[i]) * 0.5f;
      bool s = (nv >= 1.0f);
      v[i] = s ? 0.f : nv;
      sm[j0 + i][r] = s ? (u8)1 : (u8)0;
    }
    __syncthreads();
    union { uint4 u; u8 b[16]; } ov;
#pragma unroll
    for (int i = 0; i < 16; i++) ov.b[i] = sm[r][j0 + i];
    u8* op = xsT8 + ((((size_t)t * B_DIM + b) * N_DIM) + n0 + r) * C_DIM + c0 + j0;
    *(uint4*)op = ov.u;
  }
}

// ---------------------------------------------------------------------------
// K2: QKV conv1x1 + BN + LIF. 512 threads (8 waves), 64m x 256n block tile,
// wave tile 32m x 64n (2 m-strips x 4 n-strips; acc[2][4]). TWO bf16 planes.
// (Round-8 engine; pre-barrier waits hardened with lgkmcnt(0) - free, since
// all ds_reads are consumed by MFMAs before this point.)
// Depth-2 counted-vmcnt pipeline: 4 rotating LDS buffers, 1 s_barrier/step,
// steady s_waitcnt vmcnt(4). Uniform 2 gload16/wave/stage.
// Outputs:
//    q -> qs8T[t,b,n,c] u8 (transposed, uchar4 stores)  [K4 B-operand]
//    k -> ks8 [t,b,c,n] u8                              [K3 A-operand]
//    v -> vout[t,b,h,n,d] fp32 0/1 (out1)  +  vs8T[t,b,h,e,n] u8 [K3 B-op]
// ---------------------------------------------------------------------------
__global__ __launch_bounds__(512, 4) void k2_qkv(
    const u8* __restrict__ xsT8, const ushort_t* __restrict__ Sqkv,
    const float* __restrict__ qsc, const float* __restrict__ qbi,
    const float* __restrict__ ksc, const float* __restrict__ kbi,
    const float* __restrict__ vsc, const float* __restrict__ vbi,
    u8* __restrict__ qs8T, u8* __restrict__ ks8, float* __restrict__ vout,
    u8* __restrict__ vs8T)
{
  const int lin = blockIdx.x + blockIdx.y * 24;        // 0..767
  const int b   = (lin & 7) | (((lin >> 3) & 3) << 3); // XCD = lin%8 = b%8
  const int mt  = lin >> 5;                            // 0..23
  const int branch = mt >> 3;
  const int mloc = (mt & 7) * 64;
  const ushort_t* Ws = Sqkv + (size_t)branch * 3 * 262144;
  const float* scp = (branch == 0) ? qsc : ((branch == 1) ? ksc : vsc);
  const float* bip = (branch == 0) ? qbi : ((branch == 1) ? kbi : vbi);

  __shared__ alignas(16) ushort_t As[4][2][64][32];   // 32 KB, linear dest
  __shared__ alignas(16) u8 Bs8[4][256][32];          // 32 KB, linear dest

  const int tid  = threadIdx.x;
  const int lane = tid & 63;
  const int wave = tid >> 6;
  const int wm   = wave >> 2;          // 0..1 m-strip (32 rows)
  const int wn   = wave & 3;           // 0..3 n-strip (64 cols)
  const int frow = lane & 15;
  const int fsl  = lane >> 4;          // 8-elem slot 0..3
  // lane-invariant frag swizzles (row bits 1..3 come from frow only)
  const int aswc = (fsl ^ ((frow >> 1) & 3)) * 8;                              // ushort units
  const int bswc = (((fsl >> 1) ^ (((frow >> 2) ^ (frow >> 3)) & 1)) << 4)
                 + ((fsl & 1) << 3);                                           // bytes

  const u8* Bb0 = xsT8 + (size_t)b * N_DIM * C_DIM;

  const int a0p = wave >> 2, a0q = wave & 3;
  const int arl = lane >> 2;                              // row within 16
  const int acl = (((lane & 3) ^ ((arl >> 1) & 3)) * 8);  // swizzled 16B slot (ushort units)
  const int brl = lane >> 1;                              // row within 32
  const int bcl = (((lane & 1) ^ ((brl >> 2) & 1) ^ ((brl >> 3) & 1)) * 16); // swizzled 16B half (bytes)
  const int cbx = wave;

#define K2_STAGE(s_) {                                                                     \
    const int ss_ = (s_);                                                                  \
    const int t_ = ss_ >> 4; const int kb_ = (ss_ & 15) * 32; const int bf_ = ss_ & 3;     \
    gload16(Ws + (size_t)a0p * 262144 + (size_t)(mloc + a0q * 16 + arl) * 512 + kb_ + acl, \
            &As[bf_][a0p][a0q * 16][0]);                                                   \
    gload16(Bb0 + (size_t)t_ * (B_DIM * N_DIM * C_DIM) + (size_t)(cbx * 32 + brl) * 512 + kb_ + bcl, \
            &Bs8[bf_][cbx * 32][0]);                                                       \
  }

  f32x4 acc[8];
  float vst[32];
#pragma unroll
  for (int i = 0; i < 32; i++) vst[i] = 0.f;
#pragma unroll
  for (int j = 0; j < 8; j++) acc[j] = (f32x4){0.f, 0.f, 0.f, 0.f};

  const int crow0 = (lane >> 4) * 4;
  const int cn    = lane & 15;
  float sc8[2][4], bi8[2][4];
#pragma unroll
  for (int mi = 0; mi < 2; mi++)
#pragma unroll
    for (int r = 0; r < 4; r++) {
      int c = mloc + wm * 32 + mi * 16 + crow0 + r;
      sc8[mi][r] = scp[c]; bi8[mi][r] = bip[c];
    }

  K2_STAGE(0);
  K2_STAGE(1);

  for (int s = 0; s < 64; s++) {
    const int cur = s & 3;
    if (s < 62) K2_STAGE(s + 2);

    if (s < 62)       asm volatile("s_waitcnt vmcnt(4) lgkmcnt(0)" ::: "memory");
    else if (s == 62) asm volatile("s_waitcnt vmcnt(2) lgkmcnt(0)" ::: "memory");
    else              asm volatile("s_waitcnt vmcnt(0) lgkmcnt(0)" ::: "memory");
    __builtin_amdgcn_s_barrier();
    __builtin_amdgcn_sched_barrier(0);

    bf16x8 bfr[4];
#pragma unroll
    for (int nj = 0; nj < 4; nj++)
      bfr[nj] = expand_spikes(*(const uint2*)&Bs8[cur][wn * 64 + nj * 16 + frow][bswc]);

#pragma unroll
    for (int mi = 0; mi < 2; mi++) {
      const int ar = wm * 32 + mi * 16 + frow;
      bf16x8 a0 = *(const bf16x8*)&As[cur][0][ar][aswc];
      bf16x8 a1 = *(const bf16x8*)&As[cur][1][ar][aswc];
#pragma unroll
      for (int nj = 0; nj < 4; nj++) {
        acc[mi * 4 + nj] = __builtin_amdgcn_mfma_f32_16x16x32_bf16(a0, bfr[nj], acc[mi * 4 + nj], 0, 0, 0);
        acc[mi * 4 + nj] = __builtin_amdgcn_mfma_f32_16x16x32_bf16(a1, bfr[nj], acc[mi * 4 + nj], 0, 0, 0);
      }
    }

    if ((s & 15) == 15) {
      const int t = s >> 4;
      const size_t tb = (size_t)t * B_DIM + b;
      if (branch == 0) {
#pragma unroll
        for (int mi = 0; mi < 2; mi++) {
          const int c0 = mloc + wm * 32 + mi * 16 + crow0;
#pragma unroll
          for (int nj = 0; nj < 4; nj++) {
            const int n = wn * 64 + nj * 16 + cn;
            u8 sv[4];
#pragma unroll
            for (int r = 0; r < 4; r++) {
              float y = acc[mi * 4 + nj][r] * sc8[mi][r] + bi8[mi][r];
              const int vi = (mi * 4 + nj) * 4 + r;
              float v = vst[vi];
              v = v + (y - v) * 0.5f;
              bool sp = (v >= 1.0f);
              vst[vi] = sp ? 0.f : v;
              sv[r] = sp ? (u8)1 : (u8)0;
            }
            *(uchar4*)(qs8T + (tb * N_DIM + n) * C_DIM + c0) =
                make_uchar4(sv[0], sv[1], sv[2], sv[3]);
          }
        }
      } else if (branch == 1) {
#pragma unroll
        for (int mi = 0; mi < 2; mi++)
#pragma unroll
          for (int r = 0; r < 4; r++) {
            const int c = mloc + wm * 32 + mi * 16 + crow0 + r;
#pragma unroll
            for (int nj = 0; nj < 4; nj++) {
              const int n = wn * 64 + nj * 16 + cn;
              float y = acc[mi * 4 + nj][r] * sc8[mi][r] + bi8[mi][r];
              const int vi = (mi * 4 + nj) * 4 + r;
              float v = vst[vi];
              v = v + (y - v) * 0.5f;
              bool sp = (v >= 1.0f);
              vst[vi] = sp ? 0.f : v;
              ks8[(tb * C_DIM + c) * N_DIM + n] = sp ? (u8)1 : (u8)0;
            }
          }
      } else {
        const int hv = mloc >> 6;
#pragma unroll
        for (int mi = 0; mi < 2; mi++) {
          const int d0 = wm * 32 + mi * 16 + crow0;
#pragma unroll
          for (int nj = 0; nj < 4; nj++) {
            const int n = wn * 64 + nj * 16 + cn;
            float ov[4];
            u8 sv[4];
#pragma unroll
            for (int r = 0; r < 4; r++) {
              float y = acc[mi * 4 + nj][r] * sc8[mi][r] + bi8[mi][r];
              const int vi = (mi * 4 + nj) * 4 + r;
              float v = vst[vi];
              v = v + (y - v) * 0.5f;
              bool sp = (v >= 1.0f);
              vst[vi] = sp ? 0.f : v;
              ov[r] = sp ? 1.0f : 0.0f;
              sv[r] = sp ? (u8)1 : (u8)0;
            }
            *(float4*)(vout + ((tb * 8 + hv) * N_DIM + n) * 64 + d0) =
                make_float4(ov[0], ov[1], ov[2], ov[3]);
#pragma unroll
            for (int r = 0; r < 4; r++)
              vs8T[((tb * 8 + hv) * 64 + d0 + r) * N_DIM + n] = sv[r];
          }
        }
      }
#pragma unroll
      for (int j = 0; j < 8; j++) acc[j] = (f32x4){0.f, 0.f, 0.f, 0.f};
    }
  }
#undef K2_STAGE
}

// ---------------------------------------------------------------------------
// K3 (i8 MFMA, exact): attn[d,e] = (1/16) * sum_{t,n} K[d,tn]*V[tn,e].
// Both operands 0/1 spikes consumed raw as i8; i32 acc = exact counts.
// Output attnT2 = attn^T as exact 2-plane bf16, layout [blk][p][ks2][e][32d].
// ---------------------------------------------------------------------------
__global__ __launch_bounds__(256) void k3_attn(
    const u8* __restrict__ ks8, const u8* __restrict__ vs8T,
    ushort_t* __restrict__ attnT2)
{
  const int h  = blockIdx.x;
  const int b  = blockIdx.y;
  const int ch = blockIdx.z;
  __shared__ alignas(16) u8 Ks[4][64][32];
  __shared__ alignas(16) u8 Vs[4][64][32];
  const int tid  = threadIdx.x;
  const int lane = tid & 63;
  const int wave = tid >> 6;        // 0..3
  const int frow = lane & 15;
  const int fsl  = lane >> 4;
  const int off8 = (fsl ^ (((frow >> 3) & 1) << 1)) * 8;
  const int hsw  = (((lane & 1) ^ ((lane >> 4) & 1)) * 16);
  const int srow = lane >> 1;

#define K3_STAGE(s_) {                                                                     \
    const int ss_ = (s_);                                                                  \
    const int t_ = ch * 2 + (ss_ >> 3); const int kb_ = (ss_ & 7) * 32; const int bf_ = ss_ & 3; \
    if (wave < 2)                                                                          \
      gload16(ks8 + ((((size_t)t_ * B_DIM + b) * C_DIM) + h * 64 + wave * 32 + srow) * N_DIM + kb_ + hsw, \
              &Ks[bf_][wave * 32][0]);                                                     \
    else                                                                                   \
      gload16(vs8T + ((((size_t)t_ * B_DIM + b) * 8 + h) * 64 + (wave - 2) * 32 + srow) * N_DIM + kb_ + hsw, \
              &Vs[bf_][(wave - 2) * 32][0]);                                               \
  }

  i32x4 acc[4];
#pragma unroll
  for (int i = 0; i < 4; i++) acc[i] = (i32x4){0,0,0,0};

  K3_STAGE(0);
  K3_STAGE(1);

  for (int s = 0; s < 16; s++) {
    const int cur = s & 3;
    if (s < 14) K3_STAGE(s + 2);

    if (s < 14)       asm volatile("s_waitcnt vmcnt(2) lgkmcnt(0)" ::: "memory");
    else if (s == 14) asm volatile("s_waitcnt vmcnt(1) lgkmcnt(0)" ::: "memory");
    else              asm volatile("s_waitcnt vmcnt(0) lgkmcnt(0)" ::: "memory");
    __builtin_amdgcn_s_barrier();
    __builtin_amdgcn_sched_barrier(0);

    const long aK = *(const long*)&Ks[cur][wave * 16 + frow][off8];
#pragma unroll
    for (int nt = 0; nt < 4; nt++) {
      const long bV = *(const long*)&Vs[cur][nt * 16 + frow][off8];
      acc[nt] = __builtin_amdgcn_mfma_i32_16x16x32_i8(aK, bV, acc[nt], 0, 0, 0);
    }
  }

  // epilogue: C[d][e] -> attnT2[e][d] as 2 exact bf16 planes.
  const int cn    = lane & 15;
  const int crow0 = (lane >> 4) * 4;
  const int d     = wave * 16 + crow0;
  const int ks2   = d >> 5;
  const int dl    = d & 31;
  const size_t blk = ((size_t)(ch * B_DIM + b) * 8 + h);
#pragma unroll
  for (int nt = 0; nt < 4; nt++) {
    const int e = nt * 16 + cn;
    union { ushort_t sv[4]; uint2 u; } H, M;
#pragma unroll
    for (int r = 0; r < 4; r++) {
      float a = (float)acc[nt][r] * 0.0625f;
      ushort_t hi = f2bf(a);
      float m = a - bf2f(hi);
      H.sv[r] = hi;
      M.sv[r] = f2bf(m);
    }
    *(uint2*)(attnT2 + ((blk * 2 + 0) * 2 + ks2) * 2048 + (size_t)e * 32 + dl) = H.u;
    *(uint2*)(attnT2 + ((blk * 2 + 1) * 2 + ks2) * 2048 + (size_t)e * 32 + dl) = M.u;
  }
#undef K3_STAGE
}

// ---------------------------------------------------------------------------
// K4 (bf16 MFMA): out[e,n] = sum_d attnT[e,d]*q[d,n]; LIF(0.5) over t;
// -> x2sT8[t,b,n,c] u8. (exact math)
// ---------------------------------------------------------------------------
__global__ __launch_bounds__(256) void k4_out_lif(
    const u8* __restrict__ qs8T, const ushort_t* __restrict__ attnT2,
    u8* __restrict__ x2sT8)
{
  const int h  = blockIdx.x;
  const int b  = blockIdx.y;
  const int nc = blockIdx.z;   // 0..1
  __shared__ alignas(16) ushort_t As[2][2][2][64][32];  // [ch][p][ks][e][32d] 32 KB
  __shared__ alignas(16) u8 Bs[2][128][32];             // 8 KB
  const int tid  = threadIdx.x;
  const int lane = tid & 63;
  const int wave = tid >> 6;        // 0..3
  const int wrow = wave * 16;       // e strip
  const int frow = lane & 15;
  const int fsl  = lane >> 4;
  const int arl  = lane >> 2;
  const int acl  = (((lane & 3) ^ ((arl >> 1) & 3)) * 8);
  const int brl  = lane >> 1;
  const int bcl  = (((lane & 1) ^ ((brl >> 2) & 1) ^ ((brl >> 3) & 1)) * 16);

#define K4_STAGEB(s_) {                                                                    \
    const int ss_ = (s_); const int t_ = ss_ >> 1; const int ks_ = ss_ & 1;                \
    gload16(qs8T + (((size_t)t_ * B_DIM + b) * N_DIM + nc * 128 + wave * 32 + brl) * C_DIM \
                 + h * 64 + ks_ * 32 + bcl,                                                \
            &Bs[ss_ & 1][wave * 32][0]);                                                   \
  }

#pragma unroll
  for (int i = 0; i < 8; i++) {
    const int c  = wave * 8 + i;
    const int chb = c >> 4, c4 = c & 15;
    const int p = c4 >> 3, ks = (c4 >> 2) & 1, g = c4 & 3;
    const size_t blk = ((size_t)(chb * B_DIM + b) * 8 + h);
    gload16(attnT2 + (((blk * 2 + p) * 2 + ks) * 64 + g * 16 + arl) * 32 + acl,
            &As[chb][p][ks][g * 16][0]);
  }
  K4_STAGEB(0);
  asm volatile("s_waitcnt vmcnt(0) lgkmcnt(0)" ::: "memory");
  __builtin_amdgcn_s_barrier();
  __builtin_amdgcn_sched_barrier(0);

  f32x4 acc[8];
  float vst[32];
#pragma unroll
  for (int i = 0; i < 32; i++) vst[i] = 0.f;

  const int cn    = lane & 15;
  const int crow0 = (lane >> 4) * 4;

  for (int sg = 0; sg < 8; sg++) {
    const int cur = sg & 1;
    if (sg < 7) K4_STAGEB(sg + 1);

    const int chb = sg >> 2, ks = sg & 1;
    if (ks == 0) {
#pragma unroll
      for (int j = 0; j < 8; j++) acc[j] = (f32x4){0.f, 0.f, 0.f, 0.f};
    }

    bf16x8 af[2];
    const int ar = wrow + frow;
    const int asw = (fsl ^ ((ar >> 1) & 3)) * 8;
#pragma unroll
    for (int p = 0; p < 2; p++) af[p] = *(const bf16x8*)&As[chb][p][ks][ar][asw];

#pragma unroll
    for (int j = 0; j < 8; j++) {
      const int row = j * 16 + frow;
      const int bx  = ((row >> 2) ^ (row >> 3)) & 1;
      const int bsw = (((fsl >> 1) ^ bx) << 4) + ((fsl & 1) << 3);
      bf16x8 bv = expand_spikes(*(const uint2*)&Bs[cur][row][bsw]);
#pragma unroll
      for (int p = 0; p < 2; p++)
        acc[j] = __builtin_amdgcn_mfma_f32_16x16x32_bf16(af[p], bv, acc[j], 0, 0, 0);
    }

    if (ks == 1) {
      const int t = sg >> 1;
      const size_t tb = (size_t)t * B_DIM + b;
#pragma unroll
      for (int j = 0; j < 8; j++) {
        const int n = nc * 128 + j * 16 + cn;
        u8 sv[4];
#pragma unroll
        for (int r = 0; r < 4; r++) {
          const int vi = j * 4 + r;
          float y = acc[j][r];
          float nv = vst[vi] + (y - vst[vi]) * 0.5f;
          bool sp = (nv >= 0.5f);
          vst[vi] = sp ? 0.f : nv;
          sv[r] = sp ? (u8)1 : (u8)0;
        }
        *(uchar4*)(x2sT8 + (tb * N_DIM + n) * C_DIM + h * 64 + wrow + crow0) =
            make_uchar4(sv[0], sv[1], sv[2], sv[3]);
      }
    }

    asm volatile("s_waitcnt vmcnt(0) lgkmcnt(0)" ::: "memory");
    __builtin_amdgcn_s_barrier();
    __builtin_amdgcn_sched_barrier(0);
  }
#undef K4_STAGEB
}

// ---------------------------------------------------------------------------
// K5: proj conv1x1 (+bp)*scale+bias + residual -> out0 fp32. Round-8 bf16
// engine (hardened waits): 2 planes, wave tile 32m x 64n, depth-2
// counted-vmcnt, 4 LDS buffers, uniform 2 loads/wave. Grid (tb, mt).
// ---------------------------------------------------------------------------
__global__ __launch_bounds__(512, 4) void k5_proj(
    const u8* __restrict__ x2sT8, const ushort_t* __restrict__ Sp,
    const float* __restrict__ bp, const float* __restrict__ psc,
    const float* __restrict__ pbi,
    const float* __restrict__ x, float* __restrict__ out0)
{
  const int tb = blockIdx.x;   // 0..127 (fast dim -> XCD = tb%8)
  const int mt = blockIdx.y;   // 0..7
  const int mloc = mt * 64;

  __shared__ alignas(16) ushort_t As[4][2][64][32];
  __shared__ alignas(16) u8 Bs8[4][256][32];

  const int tid  = threadIdx.x;
  const int lane = tid & 63;
  const int wave = tid >> 6;
  const int wm   = wave >> 2;
  const int wn   = wave & 3;
  const int frow = lane & 15;
  const int fsl  = lane >> 4;
  const int aswc = (fsl ^ ((frow >> 1) & 3)) * 8;
  const int bswc = (((fsl >> 1) ^ (((frow >> 2) ^ (frow >> 3)) & 1)) << 4)
                 + ((fsl & 1) << 3);

  const u8* Bb = x2sT8 + (size_t)tb * N_DIM * C_DIM;

  const int a0p = wave >> 2, a0q = wave & 3;
  const int arl = lane >> 2;
  const int acl = (((lane & 3) ^ ((arl >> 1) & 3)) * 8);
  const int brl = lane >> 1;
  const int bcl = (((lane & 1) ^ ((brl >> 2) & 1) ^ ((brl >> 3) & 1)) * 16);
  const int cbx = wave;

#define K5_STAGE(s_) {                                                                     \
    const int ss_ = (s_); const int kb_ = ss_ * 32; const int bf_ = ss_ & 3;               \
    gload16(Sp + (size_t)a0p * 262144 + (size_t)(mloc + a0q * 16 + arl) * 512 + kb_ + acl, \
            &As[bf_][a0p][a0q * 16][0]);                                                   \
    gload16(Bb + (size_t)(cbx * 32 + brl) * 512 + kb_ + bcl, &Bs8[bf_][cbx * 32][0]);      \
  }

  f32x4 acc[8];
#pragma unroll
  for (int j = 0; j < 8; j++) acc[j] = (f32x4){0.f, 0.f, 0.f, 0.f};

  K5_STAGE(0);
  K5_STAGE(1);

  for (int s = 0; s < 16; s++) {
    const int cur = s & 3;
    if (s < 14) K5_STAGE(s + 2);

    if (s < 14)       asm volatile("s_waitcnt vmcnt(4) lgkmcnt(0)" ::: "memory");
    else if (s == 14) asm volatile("s_waitcnt vmcnt(2) lgkmcnt(0)" ::: "memory");
    else              asm volatile("s_waitcnt vmcnt(0) lgkmcnt(0)" ::: "memory");
    __builtin_amdgcn_s_barrier();
    __builtin_amdgcn_sched_barrier(0);

    bf16x8 bfr[4];
#pragma unroll
    for (int nj = 0; nj < 4; nj++)
      bfr[nj] = expand_spikes(*(const uint2*)&Bs8[cur][wn * 64 + nj * 16 + frow][bswc]);

#pragma unroll
    for (int mi = 0; mi < 2; mi++) {
      const int ar = wm * 32 + mi * 16 + frow;
      bf16x8 a0 = *(const bf16x8*)&As[cur][0][ar][aswc];
      bf16x8 a1 = *(const bf16x8*)&As[cur][1][ar][aswc];
#pragma unroll
      for (int nj = 0; nj < 4; nj++) {
        acc[mi * 4 + nj] = __builtin_amdgcn_mfma_f32_16x16x32_bf16(a0, bfr[nj], acc[mi * 4 + nj], 0, 0, 0);
        acc[mi * 4 + nj] = __builtin_amdgcn_mfma_f32_16x16x32_bf16(a1, bfr[nj], acc[mi * 4 + nj], 0, 0, 0);
      }
    }
  }

  const int crow0 = (lane >> 4) * 4;
  const int cn    = lane & 15;
#pragma unroll
  for (int mi = 0; mi < 2; mi++)
#pragma unroll
    for (int r = 0; r < 4; r++) {
      const int c = mloc + wm * 32 + mi * 16 + crow0 + r;
      const float scf = psc[c];
      const float bif = pbi[c];
      const float bpf = bp[c];
#pragma unroll
      for (int nj = 0; nj < 4; nj++) {
        const int n = wn * 64 + nj * 16 + cn;
        const size_t idx = ((size_t)tb * C_DIM + c) * N_DIM + n;
        out0[idx] = (acc[mi * 4 + nj][r] + bpf) * scf + bif + x[idx];
      }
    }
#undef K5_STAGE
}

// ---------------------------------------------------------------------------
// Memory map (race-free, round-8 layout):
// d_out (128 MB): out0 bytes [0,64M) scratch until K5:
//   [0,16M)  xsT8 [K1->K2]   ; attnT2 8MB reuses [0,8M) [K3->K4] (xsT8 dead)
//   [16,32M) qs8T [K2->K4]
//   [32,48M) ks8  [K2->K3]
//   [48,64M) vs8T [K2->K3]
// out1 bytes [64,128M) = vout (fp32 v output, written by K2).
// d_ws (17.5 MB used):
//   [0,16M)   x2sT8 [K4->K5]; Sqkv 4.5MB aliases [0,4.5M) [K0->K2]
//             (safe: K2 reads Sqkv before K4 writes x2sT8)
//   [16,17.5M) Sp [K0->K5]
// ---------------------------------------------------------------------------
extern "C" void kernel_launch(void* const* d_in, const int* in_sizes, int n_in,
                              void* d_out, int out_size, void* d_ws, size_t ws_size,
                              hipStream_t stream) {
  const float* x   = (const float*)d_in[0];
  const float* Wq  = (const float*)d_in[1];
  const float* qsc = (const float*)d_in[2];
  const float* qbi = (const float*)d_in[3];
  const float* Wk  = (const float*)d_in[4];
  const float* ksc = (const float*)d_in[5];
  const float* kbi = (const float*)d_in[6];
  const float* Wv  = (const float*)d_in[7];
  const float* vsc = (const float*)d_in[8];
  const float* vbi = (const float*)d_in[9];
  const float* Wp  = (const float*)d_in[10];
  const float* bp  = (const float*)d_in[11];
  const float* psc = (const float*)d_in[12];
  const float* pbi = (const float*)d_in[13];

  float* out0 = (float*)d_out;
  float* out1 = out0 + 16777216;

  const size_t M16 = 16u * 1024u * 1024u;
  char* o0 = (char*)d_out;
  char* ws = (char*)d_ws;

  u8*       xsT8   = (u8*)(o0);
  ushort_t* attnT2 = (ushort_t*)(o0);
  u8*       qs8T   = (u8*)(o0 + M16);
  u8*       ks8    = (u8*)(o0 + 2 * M16);
  u8*       vs8T   = (u8*)(o0 + 3 * M16);
  u8*       x2sT8  = (u8*)(ws);
  ushort_t* Sqkv   = (ushort_t*)(ws);
  ushort_t* Sp     = (ushort_t*)(ws + M16);

  hipLaunchKernelGGL(k0_split,        dim3(512),        dim3(256), 0, stream,
                     Wq, Wk, Wv, Wp, Sqkv, Sp);
  hipLaunchKernelGGL(k1_shortcut_lif, dim3(4, 8, 32),   dim3(256), 0, stream, x, xsT8);
  hipLaunchKernelGGL(k2_qkv,          dim3(24, 32),     dim3(512), 0, stream,
                     xsT8, Sqkv, qsc, qbi, ksc, kbi, vsc, vbi, qs8T, ks8, out1, vs8T);
  hipLaunchKernelGGL(k3_attn,         dim3(8, 32, 2),   dim3(256), 0, stream,
                     ks8, vs8T, attnT2);
  hipLaunchKernelGGL(k4_out_lif,      dim3(8, 32, 2),   dim3(256), 0, stream,
                     qs8T, attnT2, x2sT8);
  hipLaunchKernelGGL(k5_proj,         dim3(128, 8),     dim3(512), 0, stream,
                     x2sT8, Sp, bp, psc, pbi, x, out0);
}